// Round 1
// baseline (297.850 us; speedup 1.0000x reference)
//
#include <hip/hip_runtime.h>

// Problem constants (from reference)
constexpr int N_CONTEXT = 9;
constexpr int C        = 26;            // N_INPUT
constexpr int WINDOW   = 2 * N_CONTEXT + 1;   // 19
constexpr int BATCH    = 64;
constexpr int TIME     = 2000;
constexpr int ROW      = WINDOW * C;    // 494 floats per output row
constexpr int ROW2     = ROW / 2;       // 247 float2 pairs per row
// total pairs = 64*2000*247 = 31,616,000 = 123,500 blocks * 256 threads (exact)

__global__ __launch_bounds__(256)
void CreateOverlappingWindows_84963043050043_kernel(const float* __restrict__ x,
                                                    float* __restrict__ out) {
    const int p = blockIdx.x * blockDim.x + threadIdx.x;   // float2 pair index
    // Exact grid: no bounds check needed (grid*block == total pairs).

    const int r  = p / ROW2;            // output row = b*TIME + t
    const int j2 = p - r * ROW2;        // pair index within row
    const int j  = j2 * 2;              // element index within row [0,494), even

    const int t = r % TIME;             // time within batch
    const int w = j / C;                // window position (uniform across the pair:
                                        // j even, so j+1 ≡ 0 mod 26 never happens)
    const int src_t = t + w - N_CONTEXT;

    float2 v = make_float2(0.0f, 0.0f);
    if ((unsigned)src_t < (unsigned)TIME) {
        // Contiguous mapping: source element = (r - 9)*26 + j, which equals
        // ((b*TIME + src_t)*26 + c) >= 0 whenever src_t is in range.
        const int off = (r - N_CONTEXT) * C + j;   // even -> 8B aligned
        v = *reinterpret_cast<const float2*>(x + off);
    }
    reinterpret_cast<float2*>(out)[p] = v;         // 2*p = r*494 + j, coalesced
}

extern "C" void kernel_launch(void* const* d_in, const int* in_sizes, int n_in,
                              void* d_out, int out_size, void* d_ws, size_t ws_size,
                              hipStream_t stream) {
    const float* x = (const float*)d_in[0];
    float* out = (float*)d_out;

    constexpr long long total_pairs = (long long)BATCH * TIME * ROW2; // 31,616,000
    constexpr int block = 256;
    constexpr int grid  = (int)(total_pairs / block);                 // 123,500 exact

    CreateOverlappingWindows_84963043050043_kernel<<<grid, block, 0, stream>>>(x, out);
}

// Round 3
// 257.781 us; speedup vs baseline: 1.1554x; 1.1554x over previous
//
#include <hip/hip_runtime.h>

// Problem constants (from reference)
constexpr int N_CONTEXT = 9;
constexpr int C         = 26;                 // N_INPUT
constexpr int WINDOW    = 2 * N_CONTEXT + 1;  // 19
constexpr int BATCH     = 64;
constexpr int TIME      = 2000;
constexpr int ROW       = WINDOW * C;         // 494 floats per output row

// Tiling: one block handles T_TILE consecutive output rows (same batch).
constexpr int T_TILE      = 16;                   // 16 | 2000 -> tiles never cross batch
constexpr int LDS_ROWS    = T_TILE + WINDOW - 1;  // 34 time steps staged
constexpr int LDS_FLOATS  = LDS_ROWS * C;         // 884
constexpr int TILE_FLOATS = T_TILE * ROW;         // 7904
constexpr int TILE_VEC4   = TILE_FLOATS / 4;      // 1976 (integral: r0 even -> 16B aligned)
constexpr int BLOCK       = 256;
constexpr int NBLOCKS     = BATCH * TIME / T_TILE; // 8000
constexpr int BATCH_FLOATS = TIME * C;             // 52000

// Native vector type: __builtin_nontemporal_store rejects HIP_vector_type
// (class), accepts clang ext_vector_type.
typedef float vfloat4 __attribute__((ext_vector_type(4)));

__global__ __launch_bounds__(BLOCK)
void CreateOverlappingWindows_84963043050043_kernel(const float* __restrict__ x,
                                                    float* __restrict__ out) {
    __shared__ float lds[LDS_FLOATS];
    const int blk = blockIdx.x;
    const int tid = threadIdx.x;
    const int r0  = blk * T_TILE;          // first output row of tile (even)
    const int b   = r0 / TIME;             // batch index (tile is batch-uniform)
    const int lo  = b * BATCH_FLOATS;      // valid flat-index range for this batch
    const int hi  = lo + BATCH_FLOATS;
    const int g0  = (r0 - N_CONTEXT) * C;  // may be negative at t=0 edge

    // Phase 1: stage x[b, t0-9 .. t0+T_TILE+8, :] into LDS, zeros materialized
    // for out-of-range times. Validity == flat index within this batch's range
    // (no division needed: t in [0,TIME) <=> flat in [lo,hi) for c in [0,C)).
    #pragma unroll
    for (int it = 0; it < (LDS_FLOATS + BLOCK - 1) / BLOCK; ++it) {
        int idx = tid + it * BLOCK;
        if (idx < LDS_FLOATS) {
            int g = g0 + idx;
            lds[idx] = (g >= lo && g < hi) ? x[g] : 0.0f;
        }
    }
    __syncthreads();

    // Phase 2: emit the tile as aligned float4 stores.
    // Output element (lt, j) with j = w*26+c reads source (lt+w)*26+c
    //   = LDS flat index lt*26 + j  -> each row is a CONTIGUOUS 494-float
    // LDS window starting at lt*26. Only straddle case within a float4
    // (f = 4q, j even) is j == 492: elements 2,3 wrap to row lt+1
    // (address -468), handled branchlessly.
    vfloat4* out4 = reinterpret_cast<vfloat4*>(out) + (size_t)blk * TILE_VEC4;
    #pragma unroll
    for (int it = 0; it < (TILE_VEC4 + BLOCK - 1) / BLOCK; ++it) {
        int q = tid + it * BLOCK;
        if (q < TILE_VEC4) {
            int f  = q * 4;                 // float index within tile
            int lt = f / ROW;               // local row 0..15 (compiler magic-mul)
            int j  = f - lt * ROW;          // even, 0..492
            int a  = lt * C + j;            // LDS window address
            int sub = (j == ROW - 2) ? (ROW - C) : 0;   // 492 -> subtract 468
            vfloat4 v;
            v.x = lds[a];
            v.y = lds[a + 1];
            v.z = lds[a + 2 - sub];
            v.w = lds[a + 3 - sub];
            __builtin_nontemporal_store(v, &out4[q]);   // write-once stream
        }
    }
}

extern "C" void kernel_launch(void* const* d_in, const int* in_sizes, int n_in,
                              void* d_out, int out_size, void* d_ws, size_t ws_size,
                              hipStream_t stream) {
    const float* x = (const float*)d_in[0];
    float* out = (float*)d_out;
    CreateOverlappingWindows_84963043050043_kernel<<<NBLOCKS, BLOCK, 0, stream>>>(x, out);
}